// Round 15
// baseline (1388.081 us; speedup 1.0000x reference)
//
#include <hip/hip_runtime.h>
#include <hip/hip_bf16.h>

typedef __bf16 bf16x8 __attribute__((ext_vector_type(8)));
typedef float  f32x4  __attribute__((ext_vector_type(4)));
typedef short  s16x4  __attribute__((ext_vector_type(4)));
typedef unsigned short u16;

#define L2E 1.44269504088896f
#define SBAR  __builtin_amdgcn_s_barrier()
#define SCHED __builtin_amdgcn_sched_barrier(0)

static __device__ __forceinline__ u16 f2bf(float f) {
  unsigned u = __builtin_bit_cast(unsigned, f);
  u += 0x7fffu + ((u >> 16) & 1u);
  return (u16)(u >> 16);
}

static __device__ __forceinline__ void gld_lds16(const void* g, void* l) {
  __builtin_amdgcn_global_load_lds((const __attribute__((address_space(1))) unsigned*)g,
                                   (__attribute__((address_space(3))) unsigned*)l, 16, 0, 0);
}

// ---------------------------------------------------------------------------
__global__ __launch_bounds__(256)
void cvtk(const float* __restrict__ s, u16* __restrict__ d, int n) {
  const int i = (blockIdx.x * 256 + threadIdx.x) * 4;
  if (i >= n) return;
  const float4 f = *(const float4*)(s + i);
  s16x4 p;
  p[0] = (short)f2bf(f.x); p[1] = (short)f2bf(f.y);
  p[2] = (short)f2bf(f.z); p[3] = (short)f2bf(f.w);
  *(s16x4*)(d + i) = p;
}

// ---------------------------------------------------------------------------
__global__ __launch_bounds__(256)
void lnk(const float* __restrict__ x, const float* __restrict__ gw,
         const float* __restrict__ bw, u16* __restrict__ y,
         u16* __restrict__ xv, int viewmajor) {
  const int lane = threadIdx.x & 63;
  const int tok = blockIdx.x * 4 + (threadIdx.x >> 6);
  const float* xr = x + (size_t)tok * 768;
  float4 v[3];
  float s = 0.f, sq = 0.f;
#pragma unroll
  for (int j = 0; j < 3; ++j) {
    v[j] = *(const float4*)(xr + j * 256 + lane * 4);
    s  += v[j].x + v[j].y + v[j].z + v[j].w;
    sq += v[j].x * v[j].x + v[j].y * v[j].y + v[j].z * v[j].z + v[j].w * v[j].w;
  }
#pragma unroll
  for (int o = 1; o < 64; o <<= 1) { s += __shfl_xor(s, o); sq += __shfl_xor(sq, o); }
  const float mean = s * (1.f / 768.f);
  const float var  = sq * (1.f / 768.f) - mean * mean;
  const float rstd = rsqrtf(var + 1e-5f);
  size_t yrow = (size_t)tok;
  if (viewmajor) {
    const int b_ = tok >> 14, vv = (tok >> 13) & 1, l_ = tok & 8191;
    yrow = ((size_t)((vv << 2) + b_) << 13) + l_;
  }
#pragma unroll
  for (int j = 0; j < 3; ++j) {
    const float4 g4 = *(const float4*)(gw + j * 256 + lane * 4);
    const float4 b4 = *(const float4*)(bw + j * 256 + lane * 4);
    s16x4 py;
    py[0] = (short)f2bf((v[j].x - mean) * rstd * g4.x + b4.x);
    py[1] = (short)f2bf((v[j].y - mean) * rstd * g4.y + b4.y);
    py[2] = (short)f2bf((v[j].z - mean) * rstd * g4.z + b4.z);
    py[3] = (short)f2bf((v[j].w - mean) * rstd * g4.w + b4.w);
    *(s16x4*)(y + yrow * 768 + j * 256 + lane * 4) = py;
    if (xv) {
      s16x4 px;
      px[0] = (short)f2bf(v[j].x); px[1] = (short)f2bf(v[j].y);
      px[2] = (short)f2bf(v[j].z); px[3] = (short)f2bf(v[j].w);
      *(s16x4*)(xv + yrow * 768 + j * 256 + lane * 4) = px;
    }
  }
}

// ---------------------------------------------------------------------------
// Merged-phase GEMM with intra-wave ks-pipelining. BM=BN=256, BK=64,
// 8 waves (2Mx4N, per-wave 128x64), 2 barriers/K-tile, XOR-swizzled LDS.
// Reads are ks-grouped into DISJOINT register arrays (bv0/avA0 = ks0,
// bv1/avA1 = ks1; avB* for mh1) and MFMAs are ks-major, so the compiler's
// fine-grained lgkmcnt lets the ks1 read-drain overlap the ks0 MFMA group
// (per-accumulator update order ks0-then-ks1 unchanged -> bit-identical).
// Sync skeleton (stage quarters, vmcnt counts, barriers) identical to the
// r14-verified audit:
// PhA(T): {bv0,avA0 | stage T+1h2 | bv1,avA1} vmcnt(8) SBAR QDk0 QDk1
// PhB(T): {avB0     | stage T+2h1 | avB1    } vmcnt(4) SBAR QDk0 QDk1
// MODE 3: C bf16 = gelu(acc+bias)          MODE 4: out fp32 += acc+bias
// MODE 5: column-pair (nt<3 ? B1,b1,C1 : B2,b2,C2), C bf16 [row][768]
// MODE 6: V fused M=65536 (B/bias by mt<128; Vt[b][h][64][8192] by row>>15)
// MODE 7: out-proj fused M=65536 (+x residual, window un-roll scatter)
// ---------------------------------------------------------------------------
template<int MODE>
__global__ __launch_bounds__(512, 2)
void gemm_bt(const u16* __restrict__ A,
             const u16* __restrict__ B1, const u16* __restrict__ B2,
             const float* __restrict__ b1, const float* __restrict__ b2,
             void* __restrict__ C1, void* __restrict__ C2,
             int N, int K,
             const float* __restrict__ xres, const int* __restrict__ idxp) {
  __shared__ char lds[131072];
  const int t = threadIdx.x;
  const int lane = t & 63;
  const int wid = t >> 6;
  const int wm = wid >> 2, wn = wid & 3;

  const int cpx = gridDim.x >> 3;
  const int bid = (blockIdx.x & 7) * cpx + (blockIdx.x >> 3);
  const int Ntiles = N >> 8;
  const int PPB = Ntiles << 3;
  const int panel = bid / PPB;
  const int rem = bid - panel * PPB;
  const int nt = rem >> 3;
  const int mt = (panel << 3) + (rem & 7);

  const u16* Bsel = B1; const float* bias = b1; int ntl = nt;
  if constexpr (MODE == 5) {
    if (nt >= 3) { Bsel = B2; bias = b2; ntl = nt - 3; }
  } else if constexpr (MODE == 6 || MODE == 7) {
    if (mt >= 128) { Bsel = B2; bias = b2; }
  }

  const int urow = t >> 3;
  const int koff = ((t & 7) ^ (urow & 7)) << 3;
  const u16* Asrc = A + (size_t)(mt * 256 + urow) * K + koff;
  const u16* Bsrc = Bsel + (size_t)(ntl * 256 + urow) * K + koff;
  const int wdst = wid << 10;

  auto stg1A = [&](int d, int kt, int q) {
    gld_lds16(Asrc + (size_t)(q * 64) * K + kt * 64,
              (char*)lds + d * 32768 + q * 8192 + wdst);
  };
  auto stg1B = [&](int d, int kt, int q) {
    gld_lds16(Bsrc + (size_t)(q * 64) * K + kt * 64,
              (char*)lds + 65536 + d * 32768 + q * 8192 + wdst);
  };

  const int c15 = lane & 15, g = lane >> 4;
  const int axor = c15 & 7;
  const char* LAb = (char*)lds + (wm * 128 + c15) * 128;
  const char* LBb = (char*)lds + 65536 + (wn * 64 + c15) * 128;

  bf16x8 bv0[4], bv1[4], avA0[4], avA1[4], avB0[4], avB1[4];
  auto rdAk = [&](int d, int mh, int ks, bf16x8* dst) {
#pragma unroll
    for (int m = 0; m < 4; ++m)
      dst[m] = *(const bf16x8*)(LAb + d * 32768 + (mh * 64 + m * 16) * 128 +
                                (((ks << 2) | g) ^ axor) * 16);
  };
  auto rdBk = [&](int d, int ks, bf16x8* dst) {
#pragma unroll
    for (int n = 0; n < 4; ++n)
      dst[n] = *(const bf16x8*)(LBb + d * 32768 + (n * 16) * 128 +
                                (((ks << 2) | g) ^ axor) * 16);
  };

  f32x4 acc[8][4] = {};
  auto QDk = [&](bf16x8* av, bf16x8* bvv, int mh) {   // 16 MFMA, one ks
    __builtin_amdgcn_s_setprio(1);
#pragma unroll
    for (int m = 0; m < 4; ++m)
#pragma unroll
      for (int n = 0; n < 4; ++n)
        acc[mh * 4 + m][n] = __builtin_amdgcn_mfma_f32_16x16x32_bf16(
            av[m], bvv[n], acc[mh * 4 + m][n], 0, 0, 0);
    __builtin_amdgcn_s_setprio(0);
  };

  const int nk = K >> 6, niter = nk >> 1, last = nk - 1;

  // prologue: T0 full (8) + T1 h1 {A q0,q2; B q0,q1} (4); wait T0 done.
  stg1A(0, 0, 0); stg1A(0, 0, 1); stg1A(0, 0, 2); stg1A(0, 0, 3);
  stg1B(0, 0, 0); stg1B(0, 0, 1); stg1B(0, 0, 2); stg1B(0, 0, 3);
  stg1A(1, 1, 0); stg1A(1, 1, 2); stg1B(1, 1, 0); stg1B(1, 1, 1);
  asm volatile("s_waitcnt vmcnt(4)" ::: "memory");
  SBAR;

  for (int it = 0; it < niter; ++it) {
    const int i2 = it * 2;
    const int t1 = i2 + 1;
    const int t2 = (i2 + 2 < nk) ? i2 + 2 : last;
    const int t3 = (i2 + 3 < nk) ? i2 + 3 : last;

    // PhA(T0): buf0 reads (mh0 + B, ks-grouped); stage T1 h2 -> buf1
    rdBk(0, 0, bv0); rdAk(0, 0, 0, avA0);
    stg1A(1, t1, 1); stg1A(1, t1, 3); stg1B(1, t1, 2); stg1B(1, t1, 3);
    rdBk(0, 1, bv1); rdAk(0, 0, 1, avA1);
    asm volatile("s_waitcnt vmcnt(8)" ::: "memory");
    SCHED; SBAR;
    QDk(avA0, bv0, 0); QDk(avA1, bv1, 0);
    // PhB(T0): buf0 reads (mh1); stage T2 h1 -> buf0
    rdAk(0, 1, 0, avB0);
    stg1A(0, t2, 0); stg1A(0, t2, 2); stg1B(0, t2, 0); stg1B(0, t2, 1);
    rdAk(0, 1, 1, avB1);
    asm volatile("s_waitcnt vmcnt(4)" ::: "memory");
    SCHED; SBAR;
    QDk(avB0, bv0, 1); QDk(avB1, bv1, 1);
    // PhA(T1): buf1; stage T2 h2 -> buf0
    rdBk(1, 0, bv0); rdAk(1, 0, 0, avA0);
    stg1A(0, t2, 1); stg1A(0, t2, 3); stg1B(0, t2, 2); stg1B(0, t2, 3);
    rdBk(1, 1, bv1); rdAk(1, 0, 1, avA1);
    asm volatile("s_waitcnt vmcnt(8)" ::: "memory");
    SCHED; SBAR;
    QDk(avA0, bv0, 0); QDk(avA1, bv1, 0);
    // PhB(T1): buf1; stage T3 h1 -> buf1
    rdAk(1, 1, 0, avB0);
    stg1A(1, t3, 0); stg1A(1, t3, 2); stg1B(1, t3, 0); stg1B(1, t3, 1);
    rdAk(1, 1, 1, avB1);
    asm volatile("s_waitcnt vmcnt(4)" ::: "memory");
    SCHED; SBAR;
    QDk(avB0, bv0, 1); QDk(avB1, bv1, 1);
  }

  int shift = 0;
  if constexpr (MODE == 7) shift = (idxp[0] & 1) ? 256 : 0;

  const int rb0 = mt * 256 + wm * 128 + (g << 2);
  const int cb_nt = (MODE == 5) ? ntl : nt;
  const int cbase = cb_nt * 256 + wn * 64 + c15;
#pragma unroll
  for (int mi = 0; mi < 8; ++mi) {
    const int row = rb0 + mi * 16;
#pragma unroll
    for (int nj = 0; nj < 4; ++nj) {
      const int col = cbase + nj * 16;
      const float bvv = bias[col];
      if constexpr (MODE == 3) {
        u16* C = (u16*)C1;
#pragma unroll
        for (int r = 0; r < 4; ++r) {
          const float u = acc[mi][nj][r] + bvv;
          const float e = __builtin_amdgcn_exp2f(-2.45546693f * u);
          C[(size_t)(row + r) * N + col] = f2bf(u / (1.f + e));
        }
      } else if constexpr (MODE == 4) {
        float* C = (float*)C1;
#pragma unroll
        for (int r = 0; r < 4; ++r) {
          const size_t idx = (size_t)(row + r) * 768 + col;
          C[idx] = C[idx] + acc[mi][nj][r] + bvv;
        }
      } else if constexpr (MODE == 5) {
        u16* C = (u16*)(nt >= 3 ? C2 : C1);
#pragma unroll
        for (int r = 0; r < 4; ++r)
          C[(size_t)(row + r) * 768 + col] = f2bf(acc[mi][nj][r] + bvv);
      } else if constexpr (MODE == 6) {
        u16* C = (u16*)(row >= 32768 ? C2 : C1);
        const int r32 = row & 32767;
        const int hh = col >> 6, dd = col & 63;
        const int b_ = r32 >> 13, l_ = r32 & 8191;
        s16x4 pk;
#pragma unroll
        for (int r = 0; r < 4; ++r) pk[r] = (short)f2bf(acc[mi][nj][r] + bvv);
        *(s16x4*)(C + (((size_t)((b_ * 12 + hh) << 6) + dd) << 13) + l_) = pk;
      } else {  // MODE 7
        float* C = (float*)C1;
        const int att = row >> 15;
        const int r32 = row & 32767;
        const int b_ = r32 >> 13, p_ = r32 & 8191;
        const int l0 = (p_ - shift) & 8191;
        const size_t rbase = ((size_t)((b_ << 1) + att) << 13) + l0;
#pragma unroll
        for (int r = 0; r < 4; ++r) {
          const size_t idx = (rbase + r) * 768 + col;
          C[idx] = xres[idx] + acc[mi][nj][r] + bvv;
        }
      }
    }
  }
}

// ---------------------------------------------------------------------------
// Windowed cross-view attention, LDS-staged K/V (r9, refcheck-passing).
// ---------------------------------------------------------------------------
__global__ __launch_bounds__(512, 2)
void attnk(const u16* __restrict__ Q1, const u16* __restrict__ K1, const u16* __restrict__ V1,
           const u16* __restrict__ Q2, const u16* __restrict__ K2, const u16* __restrict__ V2,
           u16* __restrict__ O, const int* __restrict__ idxp) {
  __shared__ char lds[131072];
  const int t = threadIdx.x;
  const int lane = t & 63;
  const int c = lane & 15, g = lane >> 4;
  const int wid = t >> 6;
  int bb = blockIdx.x;
  const int h = bb % 12; bb /= 12;
  const int w = bb & 15; bb >>= 4;
  const int b = bb & 3;
  const int a = bb >> 2;
  const int shift = (idxp[0] & 1) ? 256 : 0;

  const u16* Q  = a ? Q2 : Q1;
  const u16* Kb = a ? K2 : K1;
  const u16* Vt = a ? V2 : V1;
  const int kbase = b * 8192 + w * 512;
  const u16* Vts = Vt + ((size_t)(b * 12 + h) << 19);

  const int qrow0 = b * 8192 + w * 512 + wid * 64;
  bf16x8 qf[4][2];
#pragma unroll
  for (int q = 0; q < 4; ++q)
#pragma unroll
    for (int hf = 0; hf < 2; ++hf)
      qf[q][hf] = *(const bf16x8*)(Q + (size_t)(qrow0 + q * 16 + c) * 768 + h * 64 + hf * 32 + g * 8);

  {
    const int r0 = t >> 3, ch = t & 7;
    char* kdst = (char*)lds + (wid << 10);
#pragma unroll
    for (int p = 0; p < 8; ++p) {
      const int row = p * 64 + r0;
      gld_lds16(Kb + (size_t)(kbase + row) * 768 + h * 64 + ((ch ^ (row & 7)) << 3),
                kdst + p * 8192);
    }
    char* vdst = (char*)lds + 65536 + (wid << 10);
#pragma unroll
    for (int p = 0; p < 8; ++p) {
      const int vrow = p * 8 + wid;
      const int cg = lane ^ (vrow & 7);
      const int l = (w * 512 + cg * 8 - shift) & 8191;
      gld_lds16(Vts + (size_t)vrow * 8192 + l, vdst + p * 8192);
    }
  }
  __syncthreads();

  f32x4 oacc[4][4] = {};
  f32x4 psum[4] = {};
  const float CEXP = 0.125f * L2E;
  const char* LK = (char*)lds;
  const char* LV = (char*)lds + 65536;

  for (int kt = 0; kt < 32; ++kt) {
    const int krow = kt * 16 + c;
    const int ksw = krow & 7;
    const bf16x8 kf0 = *(const bf16x8*)(LK + krow * 128 + ((g ^ ksw) << 4));
    const bf16x8 kf1 = *(const bf16x8*)(LK + krow * 128 + (((4 | g) ^ ksw) << 4));
    s16x4 vf[4];
#pragma unroll
    for (int df = 0; df < 4; ++df) {
      const int vr = df * 16 + c;
      vf[df] = *(const s16x4*)(LV + vr * 1024 +
                               (((kt * 2 + (g >> 1)) ^ (vr & 7)) << 4) + ((g & 1) << 3));
    }

    const f32x4 z = {0.f, 0.f, 0.f, 0.f};
    s16x4 pk[4];
#pragma unroll
    for (int q = 0; q < 4; ++q) {
      f32x4 sc2 = __builtin_amdgcn_mfma_f32_16x16x32_bf16(kf0, qf[q][0], z, 0, 0, 0);
      sc2 = __builtin_amdgcn_mfma_f32_16x16x32_bf16(kf1, qf[q][1], sc2, 0, 0, 0);
      f32x4 pv;
      pv[0] = __builtin_amdgcn_exp2f(sc2[0] * CEXP);
      pv[1] = __builtin_amdgcn_exp2f(sc2[1] * CEXP);
      pv[2] = __builtin_amdgcn_exp2f(sc2[2] * CEXP);
      pv[3] = __builtin_amdgcn_exp2f(sc2[3] * CEXP);
      psum[q] += pv;
      pk[q][0] = (short)f2bf(pv[0]);
      pk[q][1] = (short)f2bf(pv[1]);
      pk[q][2] = (short)f2bf(pv[2]);
      pk[q][3] = (short)f2bf(pv[3]);
    }
#pragma unroll
    for (int df = 0; df < 4; ++df)
#pragma unroll
      for (int q = 0; q < 4; ++q)
        oacc[df][q] = __builtin_amdgcn_mfma_f32_16x16x16bf16_1k(vf[df], pk[q], oacc[df][q], 0, 0, 0);
  }

  const size_t orow0 = (size_t)(a * 32768 + qrow0);
#pragma unroll
  for (int q = 0; q < 4; ++q) {
    float ss = psum[q][0] + psum[q][1] + psum[q][2] + psum[q][3];
    ss += __shfl_xor(ss, 16);
    ss += __shfl_xor(ss, 32);
    const float inv = 1.f / ss;
#pragma unroll
    for (int df = 0; df < 4; ++df) {
      s16x4 po;
#pragma unroll
      for (int r = 0; r < 4; ++r) po[r] = (short)f2bf(oacc[df][q][r] * inv);
      *(s16x4*)(O + (orow0 + q * 16 + c) * 768 + h * 64 + df * 16 + g * 4) = po;
    }
  }
}

// ---------------------------------------------------------------------------
extern "C" void kernel_launch(void* const* d_in, const int* in_sizes, int n_in,
                              void* d_out, int out_size, void* d_ws, size_t ws_size,
                              hipStream_t stream) {
  const float* x       = (const float*)d_in[0];
  const float* ln1_g   = (const float*)d_in[1];
  const float* ln1_b   = (const float*)d_in[2];
  const float* ln2_g   = (const float*)d_in[3];
  const float* ln2_b   = (const float*)d_in[4];
  const float* a1_wqkv = (const float*)d_in[5];
  const float* a1_bqkv = (const float*)d_in[6];
  const float* a1_wo   = (const float*)d_in[7];
  const float* a1_bo   = (const float*)d_in[8];
  const float* a2_wqkv = (const float*)d_in[9];
  const float* a2_bqkv = (const float*)d_in[10];
  const float* a2_wo   = (const float*)d_in[11];
  const float* a2_bo   = (const float*)d_in[12];
  const float* fc_w    = (const float*)d_in[13];
  const float* fc_b    = (const float*)d_in[14];
  const float* proj_w  = (const float*)d_in[15];
  const float* proj_b  = (const float*)d_in[16];
  const int*   idxp    = (const int*)d_in[17];
  float* out = (float*)d_out;

  u16* p = (u16*)d_ws;
  u16* w1  = p; p += (size_t)2304 * 768;
  u16* w2  = p; p += (size_t)2304 * 768;
  u16* wo1 = p; p += (size_t)768 * 768;
  u16* wo2 = p; p += (size_t)768 * 768;
  u16* fcw = p; p += (size_t)3072 * 768;
  u16* pjw = p; p += (size_t)768 * 3072;
  u16* y   = p; p += (size_t)65536 * 768;
  u16* xv  = p; p += (size_t)65536 * 768;
  u16* Q1  = p; p += (size_t)32768 * 768;
  u16* K1  = p; p += (size_t)32768 * 768;
  u16* V1  = p; p += (size_t)32768 * 768;
  u16* Q2  = p; p += (size_t)32768 * 768;
  u16* K2  = p; p += (size_t)32768 * 768;
  u16* V2  = p; p += (size_t)32768 * 768;
  u16* Ob  = p; p += (size_t)65536 * 768;
  u16* hb  = Q1;  // MLP hidden aliases Q1..Ob

  cvtk<<<1728, 256, 0, stream>>>(a1_wqkv, w1, 2304 * 768);
  cvtk<<<1728, 256, 0, stream>>>(a2_wqkv, w2, 2304 * 768);
  cvtk<<<576,  256, 0, stream>>>(a1_wo, wo1, 768 * 768);
  cvtk<<<576,  256, 0, stream>>>(a2_wo, wo2, 768 * 768);
  cvtk<<<2304, 256, 0, stream>>>(fc_w, fcw, 3072 * 768);
  cvtk<<<2304, 256, 0, stream>>>(proj_w, pjw, 768 * 3072);

  lnk<<<16384, 256, 0, stream>>>(x, ln1_g, ln1_b, y, xv, 1);

  const size_t VS = (size_t)32768 * 768;

  // d1: [Q1 | K2] from y0 (M=32768, N=1536) -> 768 blocks, 3 full gens
  gemm_bt<5><<<768, 512, 0, stream>>>(y, w1, w2 + 768 * 768,
                                      a1_bqkv, a2_bqkv + 768,
                                      Q1, K2, 1536, 768, nullptr, idxp);
  // d2: [K1 | Q2] from y1
  gemm_bt<5><<<768, 512, 0, stream>>>(y + VS, w1 + 768 * 768, w2,
                                      a1_bqkv + 768, a2_bqkv,
                                      K1, Q2, 1536, 768, nullptr, idxp);
  // d3: V1+V2 fused over M=65536
  gemm_bt<6><<<768, 512, 0, stream>>>(xv, w1 + 2 * 768 * 768, w2 + 2 * 768 * 768,
                                      a1_bqkv + 1536, a2_bqkv + 1536,
                                      V1, V2, 768, 768, nullptr, idxp);

  attnk<<<1536, 512, 0, stream>>>(Q1, K1, V1, Q2, K2, V2, Ob, idxp);

  // d4: out-proj fused over M=65536 + residual scatter -> d_out
  gemm_bt<7><<<768, 512, 0, stream>>>(Ob, wo1, wo2, a1_bo, a2_bo,
                                      out, nullptr, 768, 768, x, idxp);

  lnk<<<16384, 256, 0, stream>>>(out, ln2_g, ln2_b, y, nullptr, 0);

  gemm_bt<3><<<3072, 512, 0, stream>>>(y, fcw, nullptr, fc_b, nullptr,
                                       hb, nullptr, 3072, 768, nullptr, idxp);

  gemm_bt<4><<<768, 512, 0, stream>>>(hb, pjw, nullptr, proj_b, nullptr,
                                      out, nullptr, 768, 3072, nullptr, idxp);
}

// Round 16
// 1369.016 us; speedup vs baseline: 1.0139x; 1.0139x over previous
//
#include <hip/hip_runtime.h>
#include <hip/hip_bf16.h>

typedef __bf16 bf16x8 __attribute__((ext_vector_type(8)));
typedef float  f32x4  __attribute__((ext_vector_type(4)));
typedef short  s16x4  __attribute__((ext_vector_type(4)));
typedef unsigned short u16;

#define L2E 1.44269504088896f
#define SBAR  __builtin_amdgcn_s_barrier()
#define SCHED __builtin_amdgcn_sched_barrier(0)

static __device__ __forceinline__ u16 f2bf(float f) {
  unsigned u = __builtin_bit_cast(unsigned, f);
  u += 0x7fffu + ((u >> 16) & 1u);
  return (u16)(u >> 16);
}

static __device__ __forceinline__ void gld_lds16(const void* g, void* l) {
  __builtin_amdgcn_global_load_lds((const __attribute__((address_space(1))) unsigned*)g,
                                   (__attribute__((address_space(3))) unsigned*)l, 16, 0, 0);
}

// ---------------------------------------------------------------------------
__global__ __launch_bounds__(256)
void cvtk(const float* __restrict__ s, u16* __restrict__ d, int n) {
  const int i = (blockIdx.x * 256 + threadIdx.x) * 4;
  if (i >= n) return;
  const float4 f = *(const float4*)(s + i);
  s16x4 p;
  p[0] = (short)f2bf(f.x); p[1] = (short)f2bf(f.y);
  p[2] = (short)f2bf(f.z); p[3] = (short)f2bf(f.w);
  *(s16x4*)(d + i) = p;
}

// ---------------------------------------------------------------------------
__global__ __launch_bounds__(256)
void lnk(const float* __restrict__ x, const float* __restrict__ gw,
         const float* __restrict__ bw, u16* __restrict__ y,
         u16* __restrict__ xv, int viewmajor) {
  const int lane = threadIdx.x & 63;
  const int tok = blockIdx.x * 4 + (threadIdx.x >> 6);
  const float* xr = x + (size_t)tok * 768;
  float4 v[3];
  float s = 0.f, sq = 0.f;
#pragma unroll
  for (int j = 0; j < 3; ++j) {
    v[j] = *(const float4*)(xr + j * 256 + lane * 4);
    s  += v[j].x + v[j].y + v[j].z + v[j].w;
    sq += v[j].x * v[j].x + v[j].y * v[j].y + v[j].z * v[j].z + v[j].w * v[j].w;
  }
#pragma unroll
  for (int o = 1; o < 64; o <<= 1) { s += __shfl_xor(s, o); sq += __shfl_xor(sq, o); }
  const float mean = s * (1.f / 768.f);
  const float var  = sq * (1.f / 768.f) - mean * mean;
  const float rstd = rsqrtf(var + 1e-5f);
  size_t yrow = (size_t)tok;
  if (viewmajor) {
    const int b_ = tok >> 14, vv = (tok >> 13) & 1, l_ = tok & 8191;
    yrow = ((size_t)((vv << 2) + b_) << 13) + l_;
  }
#pragma unroll
  for (int j = 0; j < 3; ++j) {
    const float4 g4 = *(const float4*)(gw + j * 256 + lane * 4);
    const float4 b4 = *(const float4*)(bw + j * 256 + lane * 4);
    s16x4 py;
    py[0] = (short)f2bf((v[j].x - mean) * rstd * g4.x + b4.x);
    py[1] = (short)f2bf((v[j].y - mean) * rstd * g4.y + b4.y);
    py[2] = (short)f2bf((v[j].z - mean) * rstd * g4.z + b4.z);
    py[3] = (short)f2bf((v[j].w - mean) * rstd * g4.w + b4.w);
    *(s16x4*)(y + yrow * 768 + j * 256 + lane * 4) = py;
    if (xv) {
      s16x4 px;
      px[0] = (short)f2bf(v[j].x); px[1] = (short)f2bf(v[j].y);
      px[2] = (short)f2bf(v[j].z); px[3] = (short)f2bf(v[j].w);
      *(s16x4*)(xv + yrow * 768 + j * 256 + lane * 4) = px;
    }
  }
}

// ---------------------------------------------------------------------------
// 8-phase GEMM, ONE barrier per phase (r12/r13 core — best measured).
// BM=BN=256, BK=64, 8 waves (2Mx4N, per-wave 128x64), 2 K-tiles/iter,
// vmcnt(6) at P4/P8 only, XOR-swizzled LDS.
// MODE 3: C bf16 = gelu(acc+bias)          MODE 4: out fp32 += acc+bias
// MODE 5: column-pair (nt<3 ? B1,b1,C1 : B2,b2,C2), C bf16 [row][768]
// MODE 6: V fused M=65536 (B/bias by mt<128; Vt[b][h][64][8192] by row>>15)
// MODE 7: out-proj fused M=65536 (+x residual, window un-roll scatter)
// ---------------------------------------------------------------------------
template<int MODE>
__global__ __launch_bounds__(512, 2)
void gemm_bt(const u16* __restrict__ A,
             const u16* __restrict__ B1, const u16* __restrict__ B2,
             const float* __restrict__ b1, const float* __restrict__ b2,
             void* __restrict__ C1, void* __restrict__ C2,
             int N, int K,
             const float* __restrict__ xres, const int* __restrict__ idxp) {
  __shared__ char lds[131072];
  const int t = threadIdx.x;
  const int lane = t & 63;
  const int wid = t >> 6;
  const int wm = wid >> 2, wn = wid & 3;

  const int cpx = gridDim.x >> 3;
  const int bid = (blockIdx.x & 7) * cpx + (blockIdx.x >> 3);
  const int Ntiles = N >> 8;
  const int PPB = Ntiles << 3;
  const int panel = bid / PPB;
  const int rem = bid - panel * PPB;
  const int nt = rem >> 3;
  const int mt = (panel << 3) + (rem & 7);

  const u16* Bsel = B1; const float* bias = b1; int ntl = nt;
  if constexpr (MODE == 5) {
    if (nt >= 3) { Bsel = B2; bias = b2; ntl = nt - 3; }
  } else if constexpr (MODE == 6 || MODE == 7) {
    if (mt >= 128) { Bsel = B2; bias = b2; }
  }

  const int urow = t >> 3;
  const int koff = ((t & 7) ^ (urow & 7)) << 3;
  const u16* Asrc = A + (size_t)(mt * 256 + urow) * K + koff;
  const u16* Bsrc = Bsel + (size_t)(ntl * 256 + urow) * K + koff;
  const int wdst = wid << 10;

  auto stgA = [&](int d, int kt, int u0) {
    char* base = (char*)lds + d * 32768 + wdst;
    gld_lds16(Asrc + (size_t)(u0 * 64) * K + kt * 64, base + u0 * 8192);
    gld_lds16(Asrc + (size_t)(u0 * 64 + 64) * K + kt * 64, base + u0 * 8192 + 8192);
  };
  auto stgB = [&](int d, int kt, int u0) {
    char* base = (char*)lds + 65536 + d * 32768 + wdst;
    gld_lds16(Bsrc + (size_t)(u0 * 64) * K + kt * 64, base + u0 * 8192);
    gld_lds16(Bsrc + (size_t)(u0 * 64 + 64) * K + kt * 64, base + u0 * 8192 + 8192);
  };

  const int c15 = lane & 15, g = lane >> 4;
  const int axor = c15 & 7;
  const char* LAb = (char*)lds + (wm * 128 + c15) * 128;
  const char* LBb = (char*)lds + 65536 + (wn * 64 + c15) * 128;
  bf16x8 av[4][2], bv[4][2];
  auto rdA = [&](int d, int mh) {
#pragma unroll
    for (int m = 0; m < 4; ++m)
#pragma unroll
      for (int ks = 0; ks < 2; ++ks)
        av[m][ks] = *(const bf16x8*)(LAb + d * 32768 + (mh * 64 + m * 16) * 128 +
                                     (((ks << 2) | g) ^ axor) * 16);
  };
  auto rdB = [&](int d) {
#pragma unroll
    for (int n = 0; n < 4; ++n)
#pragma unroll
      for (int ks = 0; ks < 2; ++ks)
        bv[n][ks] = *(const bf16x8*)(LBb + d * 32768 + (n * 16) * 128 +
                                     (((ks << 2) | g) ^ axor) * 16);
  };

  f32x4 acc[8][4] = {};
  auto QD = [&](int mh, int nh) {
    __builtin_amdgcn_s_setprio(1);
#pragma unroll
    for (int ks = 0; ks < 2; ++ks)
#pragma unroll
      for (int m = 0; m < 4; ++m)
#pragma unroll
        for (int n = 0; n < 2; ++n)
          acc[mh * 4 + m][nh * 2 + n] = __builtin_amdgcn_mfma_f32_16x16x32_bf16(
              av[m][ks], bv[nh * 2 + n][ks], acc[mh * 4 + m][nh * 2 + n], 0, 0, 0);
    __builtin_amdgcn_s_setprio(0);
  };

  const int nk = K >> 6, niter = nk >> 1, last = nk - 1;

  stgA(0, 0, 0); stgA(0, 0, 2); stgB(0, 0, 0); stgB(0, 0, 2);
  stgB(1, 1, 0); stgB(1, 1, 2); stgA(1, 1, 0);
  asm volatile("s_waitcnt vmcnt(6)" ::: "memory");
  SBAR;

  for (int it = 0; it < niter; ++it) {
    const int i2 = it * 2;
    const int t1 = (i2 + 1 < nk) ? i2 + 1 : last;
    const int t2 = (i2 + 2 < nk) ? i2 + 2 : last;
    const int t3 = (i2 + 3 < nk) ? i2 + 3 : last;

    // P1
    rdA(0, 0); rdB(0); stgA(1, t1, 2);
    SCHED; SBAR;
    QD(0, 0);
    // P2
    stgB(0, t2, 0);
    SCHED; SBAR;
    QD(0, 1);
    // P3
    rdA(0, 1); stgB(0, t2, 2);
    SCHED; SBAR;
    QD(1, 1);
    // P4
    stgA(0, t2, 0);
    asm volatile("s_waitcnt vmcnt(6)" ::: "memory");
    SCHED; SBAR;
    QD(1, 0);
    // P5
    rdA(1, 0); rdB(1); stgA(0, t2, 2);
    SCHED; SBAR;
    QD(0, 0);
    // P6
    stgB(1, t3, 0);
    SCHED; SBAR;
    QD(0, 1);
    // P7
    rdA(1, 1); stgB(1, t3, 2);
    SCHED; SBAR;
    QD(1, 1);
    // P8
    stgA(1, t3, 0);
    asm volatile("s_waitcnt vmcnt(6)" ::: "memory");
    SCHED; SBAR;
    QD(1, 0);
  }

  int shift = 0;
  if constexpr (MODE == 7) shift = (idxp[0] & 1) ? 256 : 0;

  const int rb0 = mt * 256 + wm * 128 + (g << 2);
  const int cb_nt = (MODE == 5) ? ntl : nt;
  const int cbase = cb_nt * 256 + wn * 64 + c15;
#pragma unroll
  for (int mi = 0; mi < 8; ++mi) {
    const int row = rb0 + mi * 16;
#pragma unroll
    for (int nj = 0; nj < 4; ++nj) {
      const int col = cbase + nj * 16;
      const float bvv = bias[col];
      if constexpr (MODE == 3) {
        u16* C = (u16*)C1;
#pragma unroll
        for (int r = 0; r < 4; ++r) {
          const float u = acc[mi][nj][r] + bvv;
          const float e = __builtin_amdgcn_exp2f(-2.45546693f * u);
          C[(size_t)(row + r) * N + col] = f2bf(u / (1.f + e));
        }
      } else if constexpr (MODE == 4) {
        float* C = (float*)C1;
#pragma unroll
        for (int r = 0; r < 4; ++r) {
          const size_t idx = (size_t)(row + r) * 768 + col;
          C[idx] = C[idx] + acc[mi][nj][r] + bvv;
        }
      } else if constexpr (MODE == 5) {
        u16* C = (u16*)(nt >= 3 ? C2 : C1);
#pragma unroll
        for (int r = 0; r < 4; ++r)
          C[(size_t)(row + r) * 768 + col] = f2bf(acc[mi][nj][r] + bvv);
      } else if constexpr (MODE == 6) {
        u16* C = (u16*)(row >= 32768 ? C2 : C1);
        const int r32 = row & 32767;
        const int hh = col >> 6, dd = col & 63;
        const int b_ = r32 >> 13, l_ = r32 & 8191;
        s16x4 pk;
#pragma unroll
        for (int r = 0; r < 4; ++r) pk[r] = (short)f2bf(acc[mi][nj][r] + bvv);
        *(s16x4*)(C + (((size_t)((b_ * 12 + hh) << 6) + dd) << 13) + l_) = pk;
      } else {  // MODE 7
        float* C = (float*)C1;
        const int att = row >> 15;
        const int r32 = row & 32767;
        const int b_ = r32 >> 13, p_ = r32 & 8191;
        const int l0 = (p_ - shift) & 8191;
        const size_t rbase = ((size_t)((b_ << 1) + att) << 13) + l0;
#pragma unroll
        for (int r = 0; r < 4; ++r) {
          const size_t idx = (rbase + r) * 768 + col;
          C[idx] = xres[idx] + acc[mi][nj][r] + bvv;
        }
      }
    }
  }
}

// ---------------------------------------------------------------------------
// Windowed cross-view attention, LDS-staged K/V, 2-stage software pipeline:
// QK^T(kt+1) MFMAs (independent) overlap softmax(kt) VALU + PV(kt) MFMAs.
// Named A/B register sets (no dynamic indexing -> no scratch). psum/oacc
// accumulation order unchanged (kt ascending).
// ---------------------------------------------------------------------------
__global__ __launch_bounds__(512, 2)
void attnk(const u16* __restrict__ Q1, const u16* __restrict__ K1, const u16* __restrict__ V1,
           const u16* __restrict__ Q2, const u16* __restrict__ K2, const u16* __restrict__ V2,
           u16* __restrict__ O, const int* __restrict__ idxp) {
  __shared__ char lds[131072];   // K @0 (64 KB), V^T @65536 (64 KB)
  const int t = threadIdx.x;
  const int lane = t & 63;
  const int c = lane & 15, g = lane >> 4;
  const int wid = t >> 6;
  int bb = blockIdx.x;
  const int h = bb % 12; bb /= 12;
  const int w = bb & 15; bb >>= 4;
  const int b = bb & 3;
  const int a = bb >> 2;
  const int shift = (idxp[0] & 1) ? 256 : 0;

  const u16* Q  = a ? Q2 : Q1;
  const u16* Kb = a ? K2 : K1;
  const u16* Vt = a ? V2 : V1;
  const int kbase = b * 8192 + w * 512;
  const u16* Vts = Vt + ((size_t)(b * 12 + h) << 19);

  const int qrow0 = b * 8192 + w * 512 + wid * 64;
  bf16x8 qf[4][2];
#pragma unroll
  for (int q = 0; q < 4; ++q)
#pragma unroll
    for (int hf = 0; hf < 2; ++hf)
      qf[q][hf] = *(const bf16x8*)(Q + (size_t)(qrow0 + q * 16 + c) * 768 + h * 64 + hf * 32 + g * 8);

  {
    const int r0 = t >> 3, ch = t & 7;
    char* kdst = (char*)lds + (wid << 10);
#pragma unroll
    for (int p = 0; p < 8; ++p) {
      const int row = p * 64 + r0;
      gld_lds16(Kb + (size_t)(kbase + row) * 768 + h * 64 + ((ch ^ (row & 7)) << 3),
                kdst + p * 8192);
    }
    char* vdst = (char*)lds + 65536 + (wid << 10);
#pragma unroll
    for (int p = 0; p < 8; ++p) {
      const int vrow = p * 8 + wid;
      const int cg = lane ^ (vrow & 7);
      const int l = (w * 512 + cg * 8 - shift) & 8191;
      gld_lds16(Vts + (size_t)vrow * 8192 + l, vdst + p * 8192);
    }
  }
  __syncthreads();

  f32x4 oacc[4][4] = {};
  f32x4 psum[4] = {};
  const float CEXP = 0.125f * L2E;
  const char* LK = (char*)lds;
  const char* LV = (char*)lds + 65536;

  auto rdK = [&](int kt, bf16x8& k0, bf16x8& k1) {
    const int krow = kt * 16 + c;
    const int ksw = krow & 7;
    k0 = *(const bf16x8*)(LK + krow * 128 + ((g ^ ksw) << 4));
    k1 = *(const bf16x8*)(LK + krow * 128 + (((4 | g) ^ ksw) << 4));
  };
  auto qk = [&](const bf16x8& k0, const bf16x8& k1, f32x4* sc) {
    const f32x4 z = {0.f, 0.f, 0.f, 0.f};
#pragma unroll
    for (int q = 0; q < 4; ++q) {
      sc[q] = __builtin_amdgcn_mfma_f32_16x16x32_bf16(k0, qf[q][0], z, 0, 0, 0);
      sc[q] = __builtin_amdgcn_mfma_f32_16x16x32_bf16(k1, qf[q][1], sc[q], 0, 0, 0);
    }
  };
  auto rdV = [&](int kt, s16x4* vf) {
#pragma unroll
    for (int df = 0; df < 4; ++df) {
      const int vr = df * 16 + c;
      vf[df] = *(const s16x4*)(LV + vr * 1024 +
                               (((kt * 2 + (g >> 1)) ^ (vr & 7)) << 4) + ((g & 1) << 3));
    }
  };
  auto smx = [&](f32x4* sc, s16x4* pk) {
#pragma unroll
    for (int q = 0; q < 4; ++q) {
      f32x4 pv;
      pv[0] = __builtin_amdgcn_exp2f(sc[q][0] * CEXP);
      pv[1] = __builtin_amdgcn_exp2f(sc[q][1] * CEXP);
      pv[2] = __builtin_amdgcn_exp2f(sc[q][2] * CEXP);
      pv[3] = __builtin_amdgcn_exp2f(sc[q][3] * CEXP);
      psum[q] += pv;
      pk[q][0] = (short)f2bf(pv[0]);
      pk[q][1] = (short)f2bf(pv[1]);
      pk[q][2] = (short)f2bf(pv[2]);
      pk[q][3] = (short)f2bf(pv[3]);
    }
  };
  auto pv16 = [&](s16x4* vf, s16x4* pk) {
#pragma unroll
    for (int df = 0; df < 4; ++df)
#pragma unroll
      for (int q = 0; q < 4; ++q)
        oacc[df][q] = __builtin_amdgcn_mfma_f32_16x16x16bf16_1k(vf[df], pk[q], oacc[df][q], 0, 0, 0);
  };

  bf16x8 k0A, k1A, k0B, k1B;
  f32x4 scA[4], scB[4];
  rdK(0, k0A, k1A);
  qk(k0A, k1A, scA);

#pragma unroll 1
  for (int kt = 0; kt < 32; kt += 2) {
    s16x4 vfc[4], pkc[4];
    // even step: QK(kt+1) overlaps softmax(kt)+PV(kt)
    rdK(kt + 1, k0B, k1B);
    rdV(kt, vfc);
    qk(k0B, k1B, scB);
    smx(scA, pkc);
    pv16(vfc, pkc);
    // odd step: QK(kt+2) overlaps softmax(kt+1)+PV(kt+1)
    if (kt + 2 < 32) { rdK(kt + 2, k0A, k1A); }
    rdV(kt + 1, vfc);
    if (kt + 2 < 32) { qk(k0A, k1A, scA); }
    smx(scB, pkc);
    pv16(vfc, pkc);
  }

  const size_t orow0 = (size_t)(a * 32768 + qrow0);
#pragma unroll
  for (int q = 0; q < 4; ++q) {
    float ss = psum[q][0] + psum[q][1] + psum[q][2] + psum[q][3];
    ss += __shfl_xor(ss, 16);
    ss += __shfl_xor(ss, 32);
    const float inv = 1.f / ss;
#pragma unroll
    for (int df = 0; df < 4; ++df) {
      s16x4 po;
#pragma unroll
      for (int r = 0; r < 4; ++r) po[r] = (short)f2bf(oacc[df][q][r] * inv);
      *(s16x4*)(O + (orow0 + q * 16 + c) * 768 + h * 64 + df * 16 + g * 4) = po;
    }
  }
}

// ---------------------------------------------------------------------------
extern "C" void kernel_launch(void* const* d_in, const int* in_sizes, int n_in,
                              void* d_out, int out_size, void* d_ws, size_t ws_size,
                              hipStream_t stream) {
  const float* x       = (const float*)d_in[0];
  const float* ln1_g   = (const float*)d_in[1];
  const float* ln1_b   = (const float*)d_in[2];
  const float* ln2_g   = (const float*)d_in[3];
  const float* ln2_b   = (const float*)d_in[4];
  const float* a1_wqkv = (const float*)d_in[5];
  const float* a1_bqkv = (const float*)d_in[6];
  const float* a1_wo   = (const float*)d_in[7];
  const float* a1_bo   = (const float*)d_in[8];
  const float* a2_wqkv = (const float*)d_in[9];
  const float* a2_bqkv = (const float*)d_in[10];
  const float* a2_wo   = (const float*)d_in[11];
  const float* a2_bo   = (const float*)d_in[12];
  const float* fc_w    = (const float*)d_in[13];
  const float* fc_b    = (const float*)d_in[14];
  const float* proj_w  = (const float*)d_in[15];
  const float* proj_b  = (const float*)d_in[16];
  const int*   idxp    = (const int*)d_in[17];
  float* out = (float*)d_out;

  u16* p = (u16*)d_ws;
  u16* w1  = p; p += (size_t)2304 * 768;
  u16* w2  = p; p += (size_t)2304 * 768;
  u16* wo1 = p; p += (size_t)768 * 768;
  u16* wo2 = p; p += (size_t)768 * 768;
  u16* fcw = p; p += (size_t)3072 * 768;
  u16* pjw = p; p += (size_t)768 * 3072;
  u16* y   = p; p += (size_t)65536 * 768;
  u16* xv  = p; p += (size_t)65536 * 768;
  u16* Q1  = p; p += (size_t)32768 * 768;
  u16* K1  = p; p += (size_t)32768 * 768;
  u16* V1  = p; p += (size_t)32768 * 768;
  u16* Q2  = p; p += (size_t)32768 * 768;
  u16* K2  = p; p += (size_t)32768 * 768;
  u16* V2  = p; p += (size_t)32768 * 768;
  u16* Ob  = p; p += (size_t)65536 * 768;
  u16* hb  = Q1;  // MLP hidden aliases Q1..Ob

  cvtk<<<1728, 256, 0, stream>>>(a1_wqkv, w1, 2304 * 768);
  cvtk<<<1728, 256, 0, stream>>>(a2_wqkv, w2, 2304 * 768);
  cvtk<<<576,  256, 0, stream>>>(a1_wo, wo1, 768 * 768);
  cvtk<<<576,  256, 0, stream>>>(a2_wo, wo2, 768 * 768);
  cvtk<<<2304, 256, 0, stream>>>(fc_w, fcw, 3072 * 768);
  cvtk<<<2304, 256, 0, stream>>>(proj_w, pjw, 768 * 3072);

  lnk<<<16384, 256, 0, stream>>>(x, ln1_g, ln1_b, y, xv, 1);

  const size_t VS = (size_t)32768 * 768;

  // d1: [Q1 | K2] from y0 (M=32768, N=1536) -> 768 blocks, 3 full gens
  gemm_bt<5><<<768, 512, 0, stream>>>(y, w1, w2 + 768 * 768,
                                      a1_bqkv, a2_bqkv + 768,
                                      Q1, K2, 1536, 768, nullptr, idxp);
  // d2: [K1 | Q2] from y1
  gemm_bt<5><<<768, 512, 0, stream>>>(y + VS, w1 + 768 * 768, w2,
                                      a1_bqkv + 768, a2_bqkv,
                                      K1, Q2, 1536, 768, nullptr, idxp);
  // d3: V1+V2 fused over M=65536
  gemm_bt<6><<<768, 512, 0, stream>>>(xv, w1 + 2 * 768 * 768, w2 + 2 * 768 * 768,
                                      a1_bqkv + 1536, a2_bqkv + 1536,
                                      V1, V2, 768, 768, nullptr, idxp);

  attnk<<<1536, 512, 0, stream>>>(Q1, K1, V1, Q2, K2, V2, Ob, idxp);

  // d4: out-proj fused over M=65536 + residual scatter -> d_out
  gemm_bt<7><<<768, 512, 0, stream>>>(Ob, wo1, wo2, a1_bo, a2_bo,
                                      out, nullptr, 768, 768, x, idxp);

  lnk<<<16384, 256, 0, stream>>>(out, ln2_g, ln2_b, y, nullptr, 0);

  gemm_bt<3><<<3072, 512, 0, stream>>>(y, fcw, nullptr, fc_b, nullptr,
                                       hb, nullptr, 3072, 768, nullptr, idxp);

  gemm_bt<4><<<768, 512, 0, stream>>>(hb, pjw, nullptr, proj_b, nullptr,
                                      out, nullptr, 768, 3072, nullptr, idxp);
}